// Round 11
// baseline (546.451 us; speedup 1.0000x reference)
//
#include <hip/hip_runtime.h>
#include <hip/hip_bf16.h>
#include <stdint.h>

#define LVLS 16
#define TSZ  524288          // hash table size per level (2^19)
#define TMASK 0x7FFFFu
#define NPTS 524288
#define P1 2654435761u
#define P2 805459861u
#define P3 3674653429u

// floor(16 * 1.5^l), hardcoded
__constant__ float RES_TAB[16] = {
    16.f, 24.f, 36.f, 54.f, 81.f, 121.f, 182.f, 273.f,
    410.f, 615.f, 922.f, 1383.f, 2075.f, 3113.f, 4670.f, 7006.f};

using f16x8 = __attribute__((ext_vector_type(8))) _Float16;
using f32x4 = __attribute__((ext_vector_type(4))) float;
using u32x8 = __attribute__((ext_vector_type(8))) uint32_t;

union PackF16 { uint32_t u; _Float16 h[2]; };

constexpr int PS = 72;    // LDS row pitch (64 cols + 8 pad)

struct WPtrs { const float* p[11]; };

// ---------------------------------------------------------------------------
// Kernel B: XCD-pinned table build + weight swizzle (merged). Unchanged.
// ---------------------------------------------------------------------------
__global__ void k_build(const float* __restrict__ ts, const float* __restrict__ td,
                        const float* __restrict__ tptr, uint2* __restrict__ Tc,
                        WPtrs wp, _Float16* __restrict__ wdst) {
    int B = blockIdx.x;
    int tid = threadIdx.x;
    if (B < 40960) {
        int c = B & 7, j = B >> 3;
        int l, i;
        if (j < 1024) {
            l = c >> 1;
            i = (c & 1) * 262144 + j * 256 + tid;
        } else if (j < 3072) {
            l = 12 + (c >> 1);
            i = (j - 1024) * 256 + tid;
        } else {
            l = 4 + c;
            i = (j - 3072) * 256 + tid;
        }
        int id = l * TSZ + i;
        float2 sv = ((const float2*)ts)[id];
        float res = RES_TAB[l];
        float tv  = tptr[0];
        float pt  = tv * res;
        float fpt = floorf(pt);
        float ft  = pt - fpt;
        uint32_t ut = (uint32_t)(int)fpt;
        uint32_t h0 = (ut * P3) & TMASK;
        uint32_t h1 = ((ut + 1u) * P3) & TMASK;
        const float2* tdl = (const float2*)td + (size_t)l * TSZ;
        float2 a = tdl[i ^ h0];
        float2 b = tdl[i ^ h1];
        PackF16 o0, o1;
        o0.h[0] = (_Float16)sv.x; o0.h[1] = (_Float16)sv.y;
        o1.h[0] = (_Float16)((1.f - ft) * a.x + ft * b.x);
        o1.h[1] = (_Float16)((1.f - ft) * a.y + ft * b.y);
        Tc[id] = make_uint2(o0.u, o1.u);
    } else {
        int id = (B - 40960) * 256 + tid;
        if (id >= 69632) return;
        const int OFF[16] = {0,2048,6144,10240,14336,18432,20480,24576,28672,
                             32768,36864,45056,49152,57344,65536,69632};
        const int KK[15]  = {32,64,64,64,64,32,64,64,64,64,128,64,64,128,64};
        const int NN[15]  = {64,64,64,64,64,64,64,64,64,64,64,64,128,64,64};
        const int PSEL[15]= {0,1,1,1,2,3,4,4,4,5,6,7,8,9,10};
        const int POFF[15]= {0,0,4096,8192,0,0,0,4096,8192,0,0,0,0,0,0};
        int m = 0;
        while (id >= OFF[m+1]) m++;
        int local = id - OFF[m];
        int jj   = local & 7;
        int lane = (local >> 3) & 63;
        int blk  = local >> 9;
        int KC   = KK[m] >> 5;
        int ct   = blk / KC;
        int kc   = blk - ct * KC;
        int k    = kc*32 + ((lane>>4)<<3) + jj;
        int n    = ct*16 + (lane & 15);
        const float* src = wp.p[PSEL[m]] + POFF[m];
        wdst[id] = (_Float16)src[k * NN[m] + n];
    }
}

// ---------------------------------------------------------------------------
// Kernel E: hash-grid encode — r6 inner loop verbatim (verified 227 us, at
// its VMEM-issue roofline). Round-11 change is DIAGNOSTIC ONLY: the single
// 4096-block dispatch is split into two 2048-block dispatches (pass 0 |
// passes 1+2) so each runs ~115 us and the top-5 profile finally surfaces
// k_build / k_mlp with full counters (they have never been visible; two
// counter-blind k_mlp theories failed in r9/r10). Work, class->XCD mapping,
// pass ordering, and L2-hot handoff are bit-identical.
// ---------------------------------------------------------------------------
__device__ __forceinline__ void gather1(const uint2* __restrict__ tcl,
                                        float px, float py, float pz,
                                        u32x8& va, u32x8& vb,
                                        float& wx, float& wy, float& wz) {
    float fx = floorf(px), fy = floorf(py), fz = floorf(pz);
    wx = px - fx; wy = py - fy; wz = pz - fz;
    uint32_t ux = (uint32_t)(int)fx, uy = (uint32_t)(int)fy, uz = (uint32_t)(int)fz;
    uint32_t hx0 = ux,     hx1 = ux + 1u;
    uint32_t hy0 = uy*P1,  hy1 = (uy+1u)*P1;
    uint32_t hz0 = uz*P2,  hz1 = (uz+1u)*P2;
#pragma unroll
    for (int cc = 0; cc < 8; cc++) {
        uint32_t idx = (((cc&1)?hx1:hx0) ^ ((cc&2)?hy1:hy0) ^ ((cc&4)?hz1:hz0)) & TMASK;
        uint2 t = tcl[idx];
        if (cc < 4) { va[(cc&3)*2+0] = t.x; va[(cc&3)*2+1] = t.y; }
        else        { vb[(cc&3)*2+0] = t.x; vb[(cc&3)*2+1] = t.y; }
    }
}

__device__ __forceinline__ void consume1(const u32x8& va, const u32x8& vb,
                                         float wx, float wy, float wz,
                                         uint32_t* __restrict__ es,
                                         uint32_t* __restrict__ ed, int p) {
    float wxa[2] = {1.f-wx, wx}, wya[2] = {1.f-wy, wy}, wza[2] = {1.f-wz, wz};
    float sA0 = 0.f, sA1 = 0.f, sD0 = 0.f, sD1 = 0.f;
#pragma unroll
    for (int cc = 0; cc < 8; cc++) {
        float w = wxa[cc&1] * wya[(cc>>1)&1] * wza[cc>>2];
        PackF16 s, d;
        s.u = (cc<4) ? va[(cc&3)*2+0] : vb[(cc&3)*2+0];
        d.u = (cc<4) ? va[(cc&3)*2+1] : vb[(cc&3)*2+1];
        sA0 += w*(float)s.h[0]; sA1 += w*(float)s.h[1];
        sD0 += w*(float)d.h[0]; sD1 += w*(float)d.h[1];
    }
    PackF16 o;
    o.h[0] = (_Float16)sA0; o.h[1] = (_Float16)sA1; es[p] = o.u;
    o.h[0] = (_Float16)sD0; o.h[1] = (_Float16)sD1; ed[p] = o.u;
}

#define MEMFENCE asm volatile("" ::: "memory")
#define PIN(a,b,c,d) asm volatile("" : "+v"(a), "+v"(b), "+v"(c), "+v"(d))

__launch_bounds__(256, 4)
__global__ void k_encode(const float* __restrict__ x,
                         const uint2* __restrict__ Tc,
                         uint32_t* __restrict__ EncS, uint32_t* __restrict__ EncD,
                         int bbase) {
    int tid = threadIdx.x;
    int c   = blockIdx.x & 7;                // XCD class
    int b   = (blockIdx.x >> 3) + bbase;     // 0..511 within class
    int l, pb, stride;
    if (b < 256) {
        l = 4 + c;
        pb = b * 256 + tid;
        stride = 65536;
    } else if (b < 384) {
        l = 12 + (c >> 1);
        pb = (c & 1) * 262144 + (b - 256) * 256 + tid;
        stride = 32768;
    } else {
        l = c >> 1;
        pb = (c & 1) * 262144 + (b - 384) * 256 + tid;
        stride = 32768;
    }
    const uint2* tcl = Tc + (size_t)l * TSZ;
    uint32_t* es = EncS + (size_t)l * NPTS;
    uint32_t* ed = EncD + (size_t)l * NPTS;
    float res = RES_TAB[l];

    float PX[8], PY[8], PZ[8];
#pragma unroll
    for (int i = 0; i < 8; i++) {
        int p = pb + i * stride;
        PX[i] = x[p*3+0]*res; PY[i] = x[p*3+1]*res; PZ[i] = x[p*3+2]*res;
    }

    u32x8 A0, A1, A2, A3, B0, B1, B2, B3;
    float wA0x, wA0y, wA0z, wA1x, wA1y, wA1z;
    float wB0x, wB0y, wB0z, wB1x, wB1y, wB1z;

    gather1(tcl, PX[0], PY[0], PZ[0], A0, A1, wA0x, wA0y, wA0z);
    gather1(tcl, PX[1], PY[1], PZ[1], A2, A3, wA1x, wA1y, wA1z);
    gather1(tcl, PX[2], PY[2], PZ[2], B0, B1, wB0x, wB0y, wB0z);
    gather1(tcl, PX[3], PY[3], PZ[3], B2, B3, wB1x, wB1y, wB1z);
    MEMFENCE;
    PIN(A0, A1, A2, A3);
    consume1(A0, A1, wA0x, wA0y, wA0z, es, ed, pb + 0*stride);
    consume1(A2, A3, wA1x, wA1y, wA1z, es, ed, pb + 1*stride);
    gather1(tcl, PX[4], PY[4], PZ[4], A0, A1, wA0x, wA0y, wA0z);
    gather1(tcl, PX[5], PY[5], PZ[5], A2, A3, wA1x, wA1y, wA1z);
    MEMFENCE;
    PIN(B0, B1, B2, B3);
    consume1(B0, B1, wB0x, wB0y, wB0z, es, ed, pb + 2*stride);
    consume1(B2, B3, wB1x, wB1y, wB1z, es, ed, pb + 3*stride);
    gather1(tcl, PX[6], PY[6], PZ[6], B0, B1, wB0x, wB0y, wB0z);
    gather1(tcl, PX[7], PY[7], PZ[7], B2, B3, wB1x, wB1y, wB1z);
    MEMFENCE;
    PIN(A0, A1, A2, A3);
    consume1(A0, A1, wA0x, wA0y, wA0z, es, ed, pb + 4*stride);
    consume1(A2, A3, wA1x, wA1y, wA1z, es, ed, pb + 5*stride);
    PIN(B0, B1, B2, B3);
    consume1(B0, B1, wB0x, wB0y, wB0z, es, ed, pb + 6*stride);
    consume1(B2, B3, wB1x, wB1y, wB1z, es, ed, pb + 7*stride);
}

// ---------------------------------------------------------------------------
// Kernel M: barrier-free MLP — r10 version (interleaved encoder chains,
// equal-best 546 us total). Unchanged this round; awaiting first-ever
// counter evidence before further restructures (r9 regression, r10 neutral).
// ---------------------------------------------------------------------------
__device__ __forceinline__ void wait_lds() {
    asm volatile("s_waitcnt lgkmcnt(0)" ::: "memory");
}

template<int KC, bool RELU>
__device__ __forceinline__ void mm2(const f16x8 a[2][4], const f16x8* __restrict__ B,
                                    _Float16* dst, int m, int quad, int lane) {
#pragma unroll
    for (int ct = 0; ct < 4; ct++) {
        f32x4 acc0 = {0.f,0.f,0.f,0.f}, acc1 = {0.f,0.f,0.f,0.f};
#pragma unroll
        for (int kc = 0; kc < KC; kc++) {
            f16x8 b = B[(ct*KC+kc)*64 + lane];
            acc0 = __builtin_amdgcn_mfma_f32_16x16x32_f16(a[0][kc], b, acc0, 0, 0, 0);
            acc1 = __builtin_amdgcn_mfma_f32_16x16x32_f16(a[1][kc], b, acc1, 0, 0, 0);
        }
#pragma unroll
        for (int i = 0; i < 4; i++) {
            float v0 = acc0[i], v1 = acc1[i];
            if (RELU) { v0 = fmaxf(v0, 0.f); v1 = fmaxf(v1, 0.f); }
            dst[(0*16 + quad*4+i)*PS + ct*16 + m] = (_Float16)v0;
            dst[(1*16 + quad*4+i)*PS + ct*16 + m] = (_Float16)v1;
        }
    }
}

template<int KC>
__device__ __forceinline__ void mm2_keep(const f16x8 a[2][4], const f16x8* __restrict__ B,
                                         _Float16* dst, PackF16 P[2][8],
                                         int m, int quad, int lane) {
#pragma unroll
    for (int ct = 0; ct < 4; ct++) {
        f32x4 acc0 = {0.f,0.f,0.f,0.f}, acc1 = {0.f,0.f,0.f,0.f};
#pragma unroll
        for (int kc = 0; kc < KC; kc++) {
            f16x8 b = B[(ct*KC+kc)*64 + lane];
            acc0 = __builtin_amdgcn_mfma_f32_16x16x32_f16(a[0][kc], b, acc0, 0, 0, 0);
            acc1 = __builtin_amdgcn_mfma_f32_16x16x32_f16(a[1][kc], b, acc1, 0, 0, 0);
        }
#pragma unroll
        for (int ih = 0; ih < 2; ih++) {
            PackF16 p0, p1;
            p0.h[0] = (_Float16)acc0[ih*2+0]; p0.h[1] = (_Float16)acc0[ih*2+1];
            p1.h[0] = (_Float16)acc1[ih*2+0]; p1.h[1] = (_Float16)acc1[ih*2+1];
            P[0][ct*2+ih] = p0; P[1][ct*2+ih] = p1;
            dst[(0*16 + quad*4+ih*2+0)*PS + ct*16 + m] = p0.h[0];
            dst[(0*16 + quad*4+ih*2+1)*PS + ct*16 + m] = p0.h[1];
            dst[(1*16 + quad*4+ih*2+0)*PS + ct*16 + m] = p1.h[0];
            dst[(1*16 + quad*4+ih*2+1)*PS + ct*16 + m] = p1.h[1];
        }
    }
}

template<int KC>
__device__ __forceinline__ void read_a(const _Float16* buf, f16x8 a[2][4], int m, int quad) {
#pragma unroll
    for (int rt = 0; rt < 2; rt++)
#pragma unroll
        for (int kc = 0; kc < KC; kc++)
            a[rt][kc] = *(const f16x8*)(buf + (rt*16 + m)*PS + kc*32 + quad*8);
}

__device__ __forceinline__ void read_a128(const _Float16* Fs, const _Float16* Fd,
                                          f16x8 a[2][4], int m, int quad) {
#pragma unroll
    for (int rt = 0; rt < 2; rt++) {
#pragma unroll
        for (int kc = 0; kc < 2; kc++) {
            a[rt][kc]   = *(const f16x8*)(Fs + (rt*16 + m)*PS + kc*32 + quad*8);
            a[rt][kc+2] = *(const f16x8*)(Fd + (rt*16 + m)*PS + kc*32 + quad*8);
        }
    }
}

__device__ __forceinline__ void load_enc(const uint32_t* __restrict__ Enc,
                                         int pbase, int m, int quad, f16x8 a[2][4]) {
#pragma unroll
    for (int rt = 0; rt < 2; rt++) {
        union { uint32_t u[4]; f16x8 v; } cv;
        int p = pbase + rt*16 + m;
#pragma unroll
        for (int j = 0; j < 4; j++)
            cv.u[j] = Enc[(size_t)(quad*4 + j) * NPTS + p];
        a[rt][0] = cv.v;
    }
}

__launch_bounds__(256, 4)
__global__ void k_mlp(const uint32_t* __restrict__ EncS, const uint32_t* __restrict__ EncD,
                      const _Float16* __restrict__ Wfrag, const float* __restrict__ alphap,
                      const float* __restrict__ w2out, float* __restrict__ out) {
    __shared__ _Float16 FsB[4][32*PS];
    __shared__ _Float16 FdB[4][32*PS];
    int tid  = threadIdx.x;
    int wave = tid >> 6, lane = tid & 63;
    int m = lane & 15, quad = lane >> 4;
    int pbase = blockIdx.x * 128 + wave * 32;
    _Float16* Fs = FsB[wave];
    _Float16* Fd = FdB[wave];
    const f16x8* W8 = (const f16x8*)Wfrag;
    float alpha = alphap[0];

    f16x8 aS[2][4], aD[2][4];
    PackF16 sP[2][8], dP[2][8];

    // ---- INTERLEAVED encoder chains: S-layer k || D-layer k, one wait ----
    load_enc(EncS, pbase, m, quad, aS);
    load_enc(EncD, pbase, m, quad, aD);
    mm2<1, true>(aS, W8 + 0,    Fs, m, quad, lane);
    mm2<1, true>(aD, W8 + 2304, Fd, m, quad, lane); wait_lds();
    read_a<2>(Fs, aS, m, quad); read_a<2>(Fd, aD, m, quad);
    mm2<2, true>(aS, W8 + 256,  Fs, m, quad, lane);
    mm2<2, true>(aD, W8 + 2560, Fd, m, quad, lane); wait_lds();
    read_a<2>(Fs, aS, m, quad); read_a<2>(Fd, aD, m, quad);
    mm2<2, true>(aS, W8 + 768,  Fs, m, quad, lane);
    mm2<2, true>(aD, W8 + 3072, Fd, m, quad, lane); wait_lds();
    read_a<2>(Fs, aS, m, quad); read_a<2>(Fd, aD, m, quad);
    mm2<2, true>(aS, W8 + 1280, Fs, m, quad, lane);
    mm2<2, true>(aD, W8 + 3584, Fd, m, quad, lane); wait_lds();
    read_a<2>(Fs, aS, m, quad); read_a<2>(Fd, aD, m, quad);
    mm2_keep<2>(aS, W8 + 1792, Fs, sP, m, quad, lane);
    mm2_keep<2>(aD, W8 + 4096, Fd, dP, m, quad, lane); wait_lds();
    // ---- mlp1: 128->64 relu (reads Fs|Fd, writes Fs), 64->64 relu ----
    read_a128(Fs, Fd, aS, m, quad);
    mm2<4, true>(aS, W8 + 4608, Fs, m, quad, lane); wait_lds();
    read_a<2>(Fs, aS, m, quad);
    mm2<2, true>(aS, W8 + 5632, Fs, m, quad, lane); wait_lds();
    read_a<2>(Fs, aS, m, quad);
    // ---- out1 (64->128) fused with skip blend -> Fs (cols 0..63) | Fd ----
#pragma unroll
    for (int ct = 0; ct < 8; ct++) {
        f32x4 acc0 = {0.f,0.f,0.f,0.f}, acc1 = {0.f,0.f,0.f,0.f};
#pragma unroll
        for (int kc = 0; kc < 2; kc++) {
            f16x8 b = W8[6144 + (ct*2+kc)*64 + lane];
            acc0 = __builtin_amdgcn_mfma_f32_16x16x32_f16(aS[0][kc], b, acc0, 0, 0, 0);
            acc1 = __builtin_amdgcn_mfma_f32_16x16x32_f16(aS[1][kc], b, acc1, 0, 0, 0);
        }
        _Float16* tgt = (ct < 4) ? Fs : Fd;
        int col = (ct & 3) * 16 + m;
#pragma unroll
        for (int i = 0; i < 4; i++) {
            float f0 = (ct < 4) ? (float)sP[0][ct*2 + (i>>1)].h[i&1]
                                : (float)dP[0][(ct-4)*2 + (i>>1)].h[i&1];
            float f1 = (ct < 4) ? (float)sP[1][ct*2 + (i>>1)].h[i&1]
                                : (float)dP[1][(ct-4)*2 + (i>>1)].h[i&1];
            tgt[(0*16 + quad*4+i)*PS + col] = (_Float16)(alpha*acc0[i] + (1.f-alpha)*f0);
            tgt[(1*16 + quad*4+i)*PS + col] = (_Float16)(alpha*acc1[i] + (1.f-alpha)*f1);
        }
    }
    wait_lds();
    // ---- mlp2: 128->64 relu (reads Fs|Fd, writes Fs), 64->64 relu, dot ----
    read_a128(Fs, Fd, aS, m, quad);
    mm2<4, true>(aS, W8 + 7168, Fs, m, quad, lane); wait_lds();
    read_a<2>(Fs, aS, m, quad);
    float rsum0[4] = {0.f,0.f,0.f,0.f}, rsum1[4] = {0.f,0.f,0.f,0.f};
#pragma unroll
    for (int ct = 0; ct < 4; ct++) {
        f32x4 acc0 = {0.f,0.f,0.f,0.f}, acc1 = {0.f,0.f,0.f,0.f};
#pragma unroll
        for (int kc = 0; kc < 2; kc++) {
            f16x8 b = W8[8192 + (ct*2+kc)*64 + lane];
            acc0 = __builtin_amdgcn_mfma_f32_16x16x32_f16(aS[0][kc], b, acc0, 0, 0, 0);
            acc1 = __builtin_amdgcn_mfma_f32_16x16x32_f16(aS[1][kc], b, acc1, 0, 0, 0);
        }
        float wv = w2out[ct*16 + m];
#pragma unroll
        for (int i = 0; i < 4; i++) {
            rsum0[i] += fmaxf(acc0[i], 0.f) * wv;
            rsum1[i] += fmaxf(acc1[i], 0.f) * wv;
        }
    }
#pragma unroll
    for (int off = 1; off < 16; off <<= 1) {
#pragma unroll
        for (int i = 0; i < 4; i++) {
            rsum0[i] += __shfl_xor(rsum0[i], off, 64);
            rsum1[i] += __shfl_xor(rsum1[i], off, 64);
        }
    }
    if (m == 0) {
#pragma unroll
        for (int i = 0; i < 4; i++) {
            out[pbase + 0*16 + quad*4 + i] = rsum0[i];
            out[pbase + 1*16 + quad*4 + i] = rsum1[i];
        }
    }
}

// ---------------------------------------------------------------------------
extern "C" void kernel_launch(void* const* d_in, const int* in_sizes, int n_in,
                              void* d_out, int out_size, void* d_ws, size_t ws_size,
                              hipStream_t stream) {
    const float* x      = (const float*)d_in[0];
    const float* t      = (const float*)d_in[1];
    const float* alpha  = (const float*)d_in[2];
    const float* tab_s  = (const float*)d_in[3];
    const float* ws_in  = (const float*)d_in[4];
    const float* ws_hid = (const float*)d_in[5];
    const float* ws_out = (const float*)d_in[6];
    const float* tab_d  = (const float*)d_in[7];
    const float* wd_in  = (const float*)d_in[8];
    const float* wd_hid = (const float*)d_in[9];
    const float* wd_out = (const float*)d_in[10];
    const float* w1_in  = (const float*)d_in[11];
    const float* w1_hid = (const float*)d_in[12];
    const float* w1_out = (const float*)d_in[13];
    const float* w2_in  = (const float*)d_in[14];
    const float* w2_hid = (const float*)d_in[15];
    const float* w2_out = (const float*)d_in[16];
    float* out = (float*)d_out;

    char* ws = (char*)d_ws;
    _Float16* Wfrag = (_Float16*)ws;                       // 139264 B
    uint2*    Tc    = (uint2*)(ws + 139264);               // 64 MiB combined table
    uint32_t* EncS  = (uint32_t*)(ws + 139264 + 67108864); // 32 MiB [lvl][pt]
    uint32_t* EncD  = EncS + (size_t)LVLS * NPTS;          // 32 MiB [lvl][pt]
    size_t needed = 139264 + 67108864 + 2ull * 33554432ull;
    if (ws_size < needed) return;

    WPtrs wp;
    wp.p[0] = ws_in;  wp.p[1] = ws_hid; wp.p[2] = ws_out;
    wp.p[3] = wd_in;  wp.p[4] = wd_hid; wp.p[5] = wd_out;
    wp.p[6] = w1_in;  wp.p[7] = w1_hid; wp.p[8] = w1_out;
    wp.p[9] = w2_in;  wp.p[10] = w2_hid;

    k_build  <<<41232, 256, 0, stream>>>(tab_s, tab_d, t, Tc, wp, Wfrag);
    k_encode <<<2048,  256, 0, stream>>>(x, Tc, EncS, EncD, 0);    // pass 0
    k_encode <<<2048,  256, 0, stream>>>(x, Tc, EncS, EncD, 256);  // passes 1+2
    k_mlp    <<<NPTS/128, 256, 0, stream>>>(EncS, EncD, Wfrag, alpha, w2_out, out);
}

// Round 13
// 544.934 us; speedup vs baseline: 1.0028x; 1.0028x over previous
//
#include <hip/hip_runtime.h>
#include <hip/hip_bf16.h>
#include <stdint.h>

#define LVLS 16
#define TSZ  524288          // hash table size per level (2^19)
#define TMASK 0x7FFFFu
#define NPTS 524288
#define P1 2654435761u
#define P2 805459861u
#define P3 3674653429u

// floor(16 * 1.5^l), hardcoded
__constant__ float RES_TAB[16] = {
    16.f, 24.f, 36.f, 54.f, 81.f, 121.f, 182.f, 273.f,
    410.f, 615.f, 922.f, 1383.f, 2075.f, 3113.f, 4670.f, 7006.f};

using f16x8 = __attribute__((ext_vector_type(8))) _Float16;
using f32x4 = __attribute__((ext_vector_type(4))) float;
using u32x8 = __attribute__((ext_vector_type(8))) uint32_t;

union PackF16 { uint32_t u; _Float16 h[2]; };

constexpr int PS = 72;    // LDS row pitch (64 cols + 8 pad)

struct WPtrs { const float* p[11]; };

// ---------------------------------------------------------------------------
// Kernel B: XCD-pinned table build + weight swizzle. 4 entries per thread
// (resubmitted after infra failure; hand-verified: permutation algebra,
// block-uniform switch, 32B alignment, full coverage). k_build measured
// ~145 us for ~256 MB coalesced = 1.8 TB/s — concurrency-starved
// (1 entry/thread = ~512B in flight/wave/round). Key algebra: for
// 4-aligned e, {(e+j)^h : j in [0,4)} is the aligned block (e^h)&~3 with
// inner index j^(h&3) -> both td gathers become 2x16B float4 loads + a
// block-uniform switch unpermute (compile-time indices only). ts: 2xfloat4;
// store: 2xuint4. Class->level order (coarse, shared, EXCLUSIVE LAST for
// the L2-hot handoff) preserved exactly; shared-level duplication per
// class pair preserved (identical-value writes, benign).
// ---------------------------------------------------------------------------
__global__ void k_build(const float* __restrict__ ts, const float* __restrict__ td,
                        const float* __restrict__ tptr, uint2* __restrict__ Tc,
                        WPtrs wp, _Float16* __restrict__ wdst) {
    int B = blockIdx.x;
    int tid = threadIdx.x;
    if (B < 10240) {
        int c = B & 7, j = B >> 3;            // j 0..1279 within class
        int l, e;
        if (j < 256) {                        // coarse: half level per class
            l = c >> 1;
            e = (c & 1) * 262144 + j * 1024 + tid * 4;
        } else if (j < 768) {                 // shared: full level (dup per pair)
            l = 12 + (c >> 1);
            e = (j - 256) * 1024 + tid * 4;
        } else {                              // exclusive: full level, LAST
            l = 4 + c;
            e = (j - 768) * 1024 + tid * 4;
        }
        size_t base = (size_t)l * TSZ + (size_t)e;
        const float4* ts4 = (const float4*)ts;
        float4 s01 = ts4[base >> 1];          // entries e, e+1
        float4 s23 = ts4[(base >> 1) + 1];    // entries e+2, e+3
        float res = RES_TAB[l];
        float tv  = tptr[0];
        float pt  = tv * res;
        float fpt = floorf(pt);
        float ft  = pt - fpt;
        uint32_t ut = (uint32_t)(int)fpt;
        uint32_t h0 = (ut * P3) & TMASK;
        uint32_t h1 = ((ut + 1u) * P3) & TMASK;
        const float4* td4 = (const float4*)((const float2*)td + (size_t)l * TSZ);
        uint32_t b0 = ((uint32_t)e ^ h0) & ~3u, s0 = h0 & 3u;
        uint32_t b1 = ((uint32_t)e ^ h1) & ~3u, s1 = h1 & 3u;
        float4 A0 = td4[b0 >> 1], A1 = td4[(b0 >> 1) + 1];
        float4 B0 = td4[b1 >> 1], B1 = td4[(b1 >> 1) + 1];
        float2 a[4] = {{A0.x,A0.y},{A0.z,A0.w},{A1.x,A1.y},{A1.z,A1.w}};
        float2 b[4] = {{B0.x,B0.y},{B0.z,B0.w},{B1.x,B1.y},{B1.z,B1.w}};
        float2 sv[4] = {{s01.x,s01.y},{s01.z,s01.w},{s23.x,s23.y},{s23.z,s23.w}};
        // ap[jj] = a[jj ^ s0] with compile-time indices (s0 block-uniform)
        float2 ap[4], bp[4];
        switch (s0) {
        case 0: ap[0]=a[0]; ap[1]=a[1]; ap[2]=a[2]; ap[3]=a[3]; break;
        case 1: ap[0]=a[1]; ap[1]=a[0]; ap[2]=a[3]; ap[3]=a[2]; break;
        case 2: ap[0]=a[2]; ap[1]=a[3]; ap[2]=a[0]; ap[3]=a[1]; break;
        default:ap[0]=a[3]; ap[1]=a[2]; ap[2]=a[1]; ap[3]=a[0]; break;
        }
        switch (s1) {
        case 0: bp[0]=b[0]; bp[1]=b[1]; bp[2]=b[2]; bp[3]=b[3]; break;
        case 1: bp[0]=b[1]; bp[1]=b[0]; bp[2]=b[3]; bp[3]=b[2]; break;
        case 2: bp[0]=b[2]; bp[1]=b[3]; bp[2]=b[0]; bp[3]=b[1]; break;
        default:bp[0]=b[3]; bp[1]=b[2]; bp[2]=b[1]; bp[3]=b[0]; break;
        }
        uint32_t ow[8];
#pragma unroll
        for (int jj = 0; jj < 4; jj++) {
            PackF16 o0, o1;
            o0.h[0] = (_Float16)sv[jj].x; o0.h[1] = (_Float16)sv[jj].y;
            o1.h[0] = (_Float16)((1.f - ft) * ap[jj].x + ft * bp[jj].x);
            o1.h[1] = (_Float16)((1.f - ft) * ap[jj].y + ft * bp[jj].y);
            ow[jj*2]   = o0.u;
            ow[jj*2+1] = o1.u;
        }
        uint4* dst = (uint4*)(Tc + base);     // 32B-aligned (e % 4 == 0)
        dst[0] = make_uint4(ow[0], ow[1], ow[2], ow[3]);
        dst[1] = make_uint4(ow[4], ow[5], ow[6], ow[7]);
    } else {
        int id = (B - 10240) * 256 + tid;
        if (id >= 69632) return;
        const int OFF[16] = {0,2048,6144,10240,14336,18432,20480,24576,28672,
                             32768,36864,45056,49152,57344,65536,69632};
        const int KK[15]  = {32,64,64,64,64,32,64,64,64,64,128,64,64,128,64};
        const int NN[15]  = {64,64,64,64,64,64,64,64,64,64,64,64,128,64,64};
        const int PSEL[15]= {0,1,1,1,2,3,4,4,4,5,6,7,8,9,10};
        const int POFF[15]= {0,0,4096,8192,0,0,0,4096,8192,0,0,0,0,0,0};
        int m = 0;
        while (id >= OFF[m+1]) m++;
        int local = id - OFF[m];
        int jj   = local & 7;
        int lane = (local >> 3) & 63;
        int blk  = local >> 9;
        int KC   = KK[m] >> 5;
        int ct   = blk / KC;
        int kc   = blk - ct * KC;
        int k    = kc*32 + ((lane>>4)<<3) + jj;
        int n    = ct*16 + (lane & 15);
        const float* src = wp.p[PSEL[m]] + POFF[m];
        wdst[id] = (_Float16)src[k * NN[m] + n];
    }
}

// ---------------------------------------------------------------------------
// Kernel E: hash-grid encode — r6 version verbatim, SINGLE 4096-block
// dispatch (the r11 diagnostic split cost ~25 us of refill). At its
// VMEM-issue roofline: 227 us, reproduced 3x.
// ---------------------------------------------------------------------------
__device__ __forceinline__ void gather1(const uint2* __restrict__ tcl,
                                        float px, float py, float pz,
                                        u32x8& va, u32x8& vb,
                                        float& wx, float& wy, float& wz) {
    float fx = floorf(px), fy = floorf(py), fz = floorf(pz);
    wx = px - fx; wy = py - fy; wz = pz - fz;
    uint32_t ux = (uint32_t)(int)fx, uy = (uint32_t)(int)fy, uz = (uint32_t)(int)fz;
    uint32_t hx0 = ux,     hx1 = ux + 1u;
    uint32_t hy0 = uy*P1,  hy1 = (uy+1u)*P1;
    uint32_t hz0 = uz*P2,  hz1 = (uz+1u)*P2;
#pragma unroll
    for (int cc = 0; cc < 8; cc++) {
        uint32_t idx = (((cc&1)?hx1:hx0) ^ ((cc&2)?hy1:hy0) ^ ((cc&4)?hz1:hz0)) & TMASK;
        uint2 t = tcl[idx];
        if (cc < 4) { va[(cc&3)*2+0] = t.x; va[(cc&3)*2+1] = t.y; }
        else        { vb[(cc&3)*2+0] = t.x; vb[(cc&3)*2+1] = t.y; }
    }
}

__device__ __forceinline__ void consume1(const u32x8& va, const u32x8& vb,
                                         float wx, float wy, float wz,
                                         uint32_t* __restrict__ es,
                                         uint32_t* __restrict__ ed, int p) {
    float wxa[2] = {1.f-wx, wx}, wya[2] = {1.f-wy, wy}, wza[2] = {1.f-wz, wz};
    float sA0 = 0.f, sA1 = 0.f, sD0 = 0.f, sD1 = 0.f;
#pragma unroll
    for (int cc = 0; cc < 8; cc++) {
        float w = wxa[cc&1] * wya[(cc>>1)&1] * wza[cc>>2];
        PackF16 s, d;
        s.u = (cc<4) ? va[(cc&3)*2+0] : vb[(cc&3)*2+0];
        d.u = (cc<4) ? va[(cc&3)*2+1] : vb[(cc&3)*2+1];
        sA0 += w*(float)s.h[0]; sA1 += w*(float)s.h[1];
        sD0 += w*(float)d.h[0]; sD1 += w*(float)d.h[1];
    }
    PackF16 o;
    o.h[0] = (_Float16)sA0; o.h[1] = (_Float16)sA1; es[p] = o.u;
    o.h[0] = (_Float16)sD0; o.h[1] = (_Float16)sD1; ed[p] = o.u;
}

#define MEMFENCE asm volatile("" ::: "memory")
#define PIN(a,b,c,d) asm volatile("" : "+v"(a), "+v"(b), "+v"(c), "+v"(d))

__launch_bounds__(256, 4)
__global__ void k_encode(const float* __restrict__ x,
                         const uint2* __restrict__ Tc,
                         uint32_t* __restrict__ EncS, uint32_t* __restrict__ EncD) {
    int tid = threadIdx.x;
    int c   = blockIdx.x & 7;                // XCD class
    int b   = blockIdx.x >> 3;               // 0..511 within class
    int l, pb, stride;
    if (b < 256) {
        l = 4 + c;
        pb = b * 256 + tid;
        stride = 65536;
    } else if (b < 384) {
        l = 12 + (c >> 1);
        pb = (c & 1) * 262144 + (b - 256) * 256 + tid;
        stride = 32768;
    } else {
        l = c >> 1;
        pb = (c & 1) * 262144 + (b - 384) * 256 + tid;
        stride = 32768;
    }
    const uint2* tcl = Tc + (size_t)l * TSZ;
    uint32_t* es = EncS + (size_t)l * NPTS;
    uint32_t* ed = EncD + (size_t)l * NPTS;
    float res = RES_TAB[l];

    float PX[8], PY[8], PZ[8];
#pragma unroll
    for (int i = 0; i < 8; i++) {
        int p = pb + i * stride;
        PX[i] = x[p*3+0]*res; PY[i] = x[p*3+1]*res; PZ[i] = x[p*3+2]*res;
    }

    u32x8 A0, A1, A2, A3, B0, B1, B2, B3;
    float wA0x, wA0y, wA0z, wA1x, wA1y, wA1z;
    float wB0x, wB0y, wB0z, wB1x, wB1y, wB1z;

    gather1(tcl, PX[0], PY[0], PZ[0], A0, A1, wA0x, wA0y, wA0z);
    gather1(tcl, PX[1], PY[1], PZ[1], A2, A3, wA1x, wA1y, wA1z);
    gather1(tcl, PX[2], PY[2], PZ[2], B0, B1, wB0x, wB0y, wB0z);
    gather1(tcl, PX[3], PY[3], PZ[3], B2, B3, wB1x, wB1y, wB1z);
    MEMFENCE;
    PIN(A0, A1, A2, A3);
    consume1(A0, A1, wA0x, wA0y, wA0z, es, ed, pb + 0*stride);
    consume1(A2, A3, wA1x, wA1y, wA1z, es, ed, pb + 1*stride);
    gather1(tcl, PX[4], PY[4], PZ[4], A0, A1, wA0x, wA0y, wA0z);
    gather1(tcl, PX[5], PY[5], PZ[5], A2, A3, wA1x, wA1y, wA1z);
    MEMFENCE;
    PIN(B0, B1, B2, B3);
    consume1(B0, B1, wB0x, wB0y, wB0z, es, ed, pb + 2*stride);
    consume1(B2, B3, wB1x, wB1y, wB1z, es, ed, pb + 3*stride);
    gather1(tcl, PX[6], PY[6], PZ[6], B0, B1, wB0x, wB0y, wB0z);
    gather1(tcl, PX[7], PY[7], PZ[7], B2, B3, wB1x, wB1y, wB1z);
    MEMFENCE;
    PIN(A0, A1, A2, A3);
    consume1(A0, A1, wA0x, wA0y, wA0z, es, ed, pb + 4*stride);
    consume1(A2, A3, wA1x, wA1y, wA1z, es, ed, pb + 5*stride);
    PIN(B0, B1, B2, B3);
    consume1(B0, B1, wB0x, wB0y, wB0z, es, ed, pb + 6*stride);
    consume1(B2, B3, wB1x, wB1y, wB1z, es, ed, pb + 7*stride);
}

// ---------------------------------------------------------------------------
// Kernel M: barrier-free MLP — r10 version (interleaved encoder chains),
// measured r11: 150.5 us, MfmaUtil 20%, VALUBusy 36%, occ 42%,
// bank-conflict 3.9M cyc. Stall-bound; kept unchanged while k_build (the
// equal-size, cheaper-to-fix bottleneck) is attacked first.
// ---------------------------------------------------------------------------
__device__ __forceinline__ void wait_lds() {
    asm volatile("s_waitcnt lgkmcnt(0)" ::: "memory");
}

template<int KC, bool RELU>
__device__ __forceinline__ void mm2(const f16x8 a[2][4], const f16x8* __restrict__ B,
                                    _Float16* dst, int m, int quad, int lane) {
#pragma unroll
    for (int ct = 0; ct < 4; ct++) {
        f32x4 acc0 = {0.f,0.f,0.f,0.f}, acc1 = {0.f,0.f,0.f,0.f};
#pragma unroll
        for (int kc = 0; kc < KC; kc++) {
            f16x8 b = B[(ct*KC+kc)*64 + lane];
            acc0 = __builtin_amdgcn_mfma_f32_16x16x32_f16(a[0][kc], b, acc0, 0, 0, 0);
            acc1 = __builtin_amdgcn_mfma_f32_16x16x32_f16(a[1][kc], b, acc1, 0, 0, 0);
        }
#pragma unroll
        for (int i = 0; i < 4; i++) {
            float v0 = acc0[i], v1 = acc1[i];
            if (RELU) { v0 = fmaxf(v0, 0.f); v1 = fmaxf(v1, 0.f); }
            dst[(0*16 + quad*4+i)*PS + ct*16 + m] = (_Float16)v0;
            dst[(1*16 + quad*4+i)*PS + ct*16 + m] = (_Float16)v1;
        }
    }
}

template<int KC>
__device__ __forceinline__ void mm2_keep(const f16x8 a[2][4], const f16x8* __restrict__ B,
                                         _Float16* dst, PackF16 P[2][8],
                                         int m, int quad, int lane) {
#pragma unroll
    for (int ct = 0; ct < 4; ct++) {
        f32x4 acc0 = {0.f,0.f,0.f,0.f}, acc1 = {0.f,0.f,0.f,0.f};
#pragma unroll
        for (int kc = 0; kc < KC; kc++) {
            f16x8 b = B[(ct*KC+kc)*64 + lane];
            acc0 = __builtin_amdgcn_mfma_f32_16x16x32_f16(a[0][kc], b, acc0, 0, 0, 0);
            acc1 = __builtin_amdgcn_mfma_f32_16x16x32_f16(a[1][kc], b, acc1, 0, 0, 0);
        }
#pragma unroll
        for (int ih = 0; ih < 2; ih++) {
            PackF16 p0, p1;
            p0.h[0] = (_Float16)acc0[ih*2+0]; p0.h[1] = (_Float16)acc0[ih*2+1];
            p1.h[0] = (_Float16)acc1[ih*2+0]; p1.h[1] = (_Float16)acc1[ih*2+1];
            P[0][ct*2+ih] = p0; P[1][ct*2+ih] = p1;
            dst[(0*16 + quad*4+ih*2+0)*PS + ct*16 + m] = p0.h[0];
            dst[(0*16 + quad*4+ih*2+1)*PS + ct*16 + m] = p0.h[1];
            dst[(1*16 + quad*4+ih*2+0)*PS + ct*16 + m] = p1.h[0];
            dst[(1*16 + quad*4+ih*2+1)*PS + ct*16 + m] = p1.h[1];
        }
    }
}

template<int KC>
__device__ __forceinline__ void read_a(const _Float16* buf, f16x8 a[2][4], int m, int quad) {
#pragma unroll
    for (int rt = 0; rt < 2; rt++)
#pragma unroll
        for (int kc = 0; kc < KC; kc++)
            a[rt][kc] = *(const f16x8*)(buf + (rt*16 + m)*PS + kc*32 + quad*8);
}

__device__ __forceinline__ void read_a128(const _Float16* Fs, const _Float16* Fd,
                                          f16x8 a[2][4], int m, int quad) {
#pragma unroll
    for (int rt = 0; rt < 2; rt++) {
#pragma unroll
        for (int kc = 0; kc < 2; kc++) {
            a[rt][kc]   = *(const f16x8*)(Fs + (rt*16 + m)*PS + kc*32 + quad*8);
            a[rt][kc+2] = *(const f16x8*)(Fd + (rt*16 + m)*PS + kc*32 + quad*8);
        }
    }
}

__device__ __forceinline__ void load_enc(const uint32_t* __restrict__ Enc,
                                         int pbase, int m, int quad, f16x8 a[2][4]) {
#pragma unroll
    for (int rt = 0; rt < 2; rt++) {
        union { uint32_t u[4]; f16x8 v; } cv;
        int p = pbase + rt*16 + m;
#pragma unroll
        for (int j = 0; j < 4; j++)
            cv.u[j] = Enc[(size_t)(quad*4 + j) * NPTS + p];
        a[rt][0] = cv.v;
    }
}

__launch_bounds__(256, 4)
__global__ void k_mlp(const uint32_t* __restrict__ EncS, const uint32_t* __restrict__ EncD,
                      const _Float16* __restrict__ Wfrag, const float* __restrict__ alphap,
                      const float* __restrict__ w2out, float* __restrict__ out) {
    __shared__ _Float16 FsB[4][32*PS];
    __shared__ _Float16 FdB[4][32*PS];
    int tid  = threadIdx.x;
    int wave = tid >> 6, lane = tid & 63;
    int m = lane & 15, quad = lane >> 4;
    int pbase = blockIdx.x * 128 + wave * 32;
    _Float16* Fs = FsB[wave];
    _Float16* Fd = FdB[wave];
    const f16x8* W8 = (const f16x8*)Wfrag;
    float alpha = alphap[0];

    f16x8 aS[2][4], aD[2][4];
    PackF16 sP[2][8], dP[2][8];

    // ---- INTERLEAVED encoder chains: S-layer k || D-layer k, one wait ----
    load_enc(EncS, pbase, m, quad, aS);
    load_enc(EncD, pbase, m, quad, aD);
    mm2<1, true>(aS, W8 + 0,    Fs, m, quad, lane);
    mm2<1, true>(aD, W8 + 2304, Fd, m, quad, lane); wait_lds();
    read_a<2>(Fs, aS, m, quad); read_a<2>(Fd, aD, m, quad);
    mm2<2, true>(aS, W8 + 256,  Fs, m, quad, lane);
    mm2<2, true>(aD, W8 + 2560, Fd, m, quad, lane); wait_lds();
    read_a<2>(Fs, aS, m, quad); read_a<2>(Fd, aD, m, quad);
    mm2<2, true>(aS, W8 + 768,  Fs, m, quad, lane);
    mm2<2, true>(aD, W8 + 3072, Fd, m, quad, lane); wait_lds();
    read_a<2>(Fs, aS, m, quad); read_a<2>(Fd, aD, m, quad);
    mm2<2, true>(aS, W8 + 1280, Fs, m, quad, lane);
    mm2<2, true>(aD, W8 + 3584, Fd, m, quad, lane); wait_lds();
    read_a<2>(Fs, aS, m, quad); read_a<2>(Fd, aD, m, quad);
    mm2_keep<2>(aS, W8 + 1792, Fs, sP, m, quad, lane);
    mm2_keep<2>(aD, W8 + 4096, Fd, dP, m, quad, lane); wait_lds();
    // ---- mlp1: 128->64 relu (reads Fs|Fd, writes Fs), 64->64 relu ----
    read_a128(Fs, Fd, aS, m, quad);
    mm2<4, true>(aS, W8 + 4608, Fs, m, quad, lane); wait_lds();
    read_a<2>(Fs, aS, m, quad);
    mm2<2, true>(aS, W8 + 5632, Fs, m, quad, lane); wait_lds();
    read_a<2>(Fs, aS, m, quad);
    // ---- out1 (64->128) fused with skip blend -> Fs (cols 0..63) | Fd ----
#pragma unroll
    for (int ct = 0; ct < 8; ct++) {
        f32x4 acc0 = {0.f,0.f,0.f,0.f}, acc1 = {0.f,0.f,0.f,0.f};
#pragma unroll
        for (int kc = 0; kc < 2; kc++) {
            f16x8 b = W8[6144 + (ct*2+kc)*64 + lane];
            acc0 = __builtin_amdgcn_mfma_f32_16x16x32_f16(aS[0][kc], b, acc0, 0, 0, 0);
            acc1 = __builtin_amdgcn_mfma_f32_16x16x32_f16(aS[1][kc], b, acc1, 0, 0, 0);
        }
        _Float16* tgt = (ct < 4) ? Fs : Fd;
        int col = (ct & 3) * 16 + m;
#pragma unroll
        for (int i = 0; i < 4; i++) {
            float f0 = (ct < 4) ? (float)sP[0][ct*2 + (i>>1)].h[i&1]
                                : (float)dP[0][(ct-4)*2 + (i>>1)].h[i&1];
            float f1 = (ct < 4) ? (float)sP[1][ct*2 + (i>>1)].h[i&1]
                                : (float)dP[1][(ct-4)*2 + (i>>1)].h[i&1];
            tgt[(0*16 + quad*4+i)*PS + col] = (_Float16)(alpha*acc0[i] + (1.f-alpha)*f0);
            tgt[(1*16 + quad*4+i)*PS + col] = (_Float16)(alpha*acc1[i] + (1.f-alpha)*f1);
        }
    }
    wait_lds();
    // ---- mlp2: 128->64 relu (reads Fs|Fd, writes Fs), 64->64 relu, dot ----
    read_a128(Fs, Fd, aS, m, quad);
    mm2<4, true>(aS, W8 + 7168, Fs, m, quad, lane); wait_lds();
    read_a<2>(Fs, aS, m, quad);
    float rsum0[4] = {0.f,0.f,0.f,0.f}, rsum1[4] = {0.f,0.f,0.f,0.f};
#pragma unroll
    for (int ct = 0; ct < 4; ct++) {
        f32x4 acc0 = {0.f,0.f,0.f,0.f}, acc1 = {0.f,0.f,0.f,0.f};
#pragma unroll
        for (int kc = 0; kc < 2; kc++) {
            f16x8 b = W8[8192 + (ct*2+kc)*64 + lane];
            acc0 = __builtin_amdgcn_mfma_f32_16x16x32_f16(aS[0][kc], b, acc0, 0, 0, 0);
            acc1 = __builtin_amdgcn_mfma_f32_16x16x32_f16(aS[1][kc], b, acc1, 0, 0, 0);
        }
        float wv = w2out[ct*16 + m];
#pragma unroll
        for (int i = 0; i < 4; i++) {
            rsum0[i] += fmaxf(acc0[i], 0.f) * wv;
            rsum1[i] += fmaxf(acc1[i], 0.f) * wv;
        }
    }
#pragma unroll
    for (int off = 1; off < 16; off <<= 1) {
#pragma unroll
        for (int i = 0; i < 4; i++) {
            rsum0[i] += __shfl_xor(rsum0[i], off, 64);
            rsum1[i] += __shfl_xor(rsum1[i], off, 64);
        }
    }
    if (m == 0) {
#pragma unroll
        for (int i = 0; i < 4; i++) {
            out[pbase + 0*16 + quad*4 + i] = rsum0[i];
            out[pbase + 1*16 + quad*4 + i] = rsum1[i];
        }
    }
}

// ---------------------------------------------------------------------------
extern "C" void kernel_launch(void* const* d_in, const int* in_sizes, int n_in,
                              void* d_out, int out_size, void* d_ws, size_t ws_size,
                              hipStream_t stream) {
    const float* x      = (const float*)d_in[0];
    const float* t      = (const float*)d_in[1];
    const float* alpha  = (const float*)d_in[2];
    const float* tab_s  = (const float*)d_in[3];
    const float* ws_in  = (const float*)d_in[4];
    const float* ws_hid = (const float*)d_in[5];
    const float* ws_out = (const float*)d_in[6];
    const float* tab_d  = (const float*)d_in[7];
    const float* wd_in  = (const float*)d_in[8];
    const float* wd_hid = (const float*)d_in[9];
    const float* wd_out = (const float*)d_in[10];
    const float* w1_in  = (const float*)d_in[11];
    const float* w1_hid = (const float*)d_in[12];
    const float* w1_out = (const float*)d_in[13];
    const float* w2_in  = (const float*)d_in[14];
    const float* w2_hid = (const float*)d_in[15];
    const float* w2_out = (const float*)d_in[16];
    float* out = (float*)d_out;

    char* ws = (char*)d_ws;
    _Float16* Wfrag = (_Float16*)ws;                       // 139264 B
    uint2*    Tc    = (uint2*)(ws + 139264);               // 64 MiB combined table
    uint32_t* EncS  = (uint32_t*)(ws + 139264 + 67108864); // 32 MiB [lvl][pt]
    uint32_t* EncD  = EncS + (size_t)LVLS * NPTS;          // 32 MiB [lvl][pt]
    size_t needed = 139264 + 67108864 + 2ull * 33554432ull;
    if (ws_size < needed) return;

    WPtrs wp;
    wp.p[0] = ws_in;  wp.p[1] = ws_hid; wp.p[2] = ws_out;
    wp.p[3] = wd_in;  wp.p[4] = wd_hid; wp.p[5] = wd_out;
    wp.p[6] = w1_in;  wp.p[7] = w1_hid; wp.p[8] = w1_out;
    wp.p[9] = w2_in;  wp.p[10] = w2_hid;

    k_build  <<<10512, 256, 0, stream>>>(tab_s, tab_d, t, Tc, wp, Wfrag);
    k_encode <<<4096,  256, 0, stream>>>(x, Tc, EncS, EncD);
    k_mlp    <<<NPTS/128, 256, 0, stream>>>(EncS, EncD, Wfrag, alpha, w2_out, out);
}